// Round 3
// baseline (149.080 us; speedup 1.0000x reference)
//
#include <hip/hip_runtime.h>

namespace {

constexpr int B = 16;
constexpr int C = 1024;
constexpr int BC = B * C;                          // 16384
constexpr long long BCC = (long long)B * C * C;    // 16777216
constexpr float EPS  = 1e-12f;
constexpr float TINY = 1e-9f;
constexpr int TI = 8;                              // rows per block (4 waves x 2 rows)

using f32x4 = __attribute__((ext_vector_type(4))) float;

// =====================================================================
// Kernel A: per-row scalar pass. R2 structure WITHOUT the 134 MB coef
// stores. All row-loop operands staged in LDS (incl. l_j) so no global
// loads mix with stores. Writes 8-float pack per row to ws + 4 small outs.
// ws[row*8 + {0:m_u*e_li, 1:m_u*e_ui, 2:w_i, 3:m_l*e_mi, 4:dl, 5:du}]
// =====================================================================
__global__ __launch_bounds__(256) void rowscalar_kernel(
    const float* __restrict__ lower,
    const float* __restrict__ upper,
    float* __restrict__ out,
    float* __restrict__ ws)
{
    const int tid  = threadIdx.x;
    const int lane = tid & 63;
    const int wid  = tid >> 6;
    constexpr int rowsPerBatch = C / TI;           // 128
    const int b  = blockIdx.x / rowsPerBatch;
    const int i0 = (blockIdx.x % rowsPerBatch) * TI;

    const float* __restrict__ lrow = lower + b * C;
    const float* __restrict__ urow = upper + b * C;

    __shared__ float sEl[C], sEu[C], sWk[C], sLj[C];   // 16 KB
    __shared__ float red0[4][4];

    const f32x4 lj4 = *reinterpret_cast<const f32x4*>(lrow + tid * 4);
    const f32x4 uj4 = *reinterpret_cast<const f32x4*>(urow + tid * 4);
    f32x4 tEl, tEu, tWk;
    float s0 = 0.f, s1 = 0.f, s2 = 0.f, s3 = 0.f;  // sum El, Eu, Em, m*Em
    #pragma unroll
    for (int k = 0; k < 4; ++k) {
        const float lj = lj4[k];
        const float uj = uj4[k];
        const float El = __expf(lj);
        const float Eu = __expf(uj);
        const float mk = 0.5f * (lj + uj);
        const float Em = __expf(mk);
        tEl[k] = El; tEu[k] = Eu; tWk[k] = uj - lj;
        s0 += El; s1 += Eu; s2 += Em; s3 += mk * Em;
    }
    *reinterpret_cast<f32x4*>(&sEl[tid * 4]) = tEl;
    *reinterpret_cast<f32x4*>(&sEu[tid * 4]) = tEu;
    *reinterpret_cast<f32x4*>(&sWk[tid * 4]) = tWk;
    *reinterpret_cast<f32x4*>(&sLj[tid * 4]) = lj4;
    #pragma unroll
    for (int o = 32; o > 0; o >>= 1) {
        s0 += __shfl_down(s0, o);
        s1 += __shfl_down(s1, o);
        s2 += __shfl_down(s2, o);
        s3 += __shfl_down(s3, o);
    }
    if (lane == 0) {
        red0[wid][0] = s0; red0[wid][1] = s1;
        red0[wid][2] = s2; red0[wid][3] = s3;
    }
    __syncthreads();                               // the only barrier
    const float SEl  = red0[0][0] + red0[1][0] + red0[2][0] + red0[3][0];
    const float SEu  = red0[0][1] + red0[1][1] + red0[2][1] + red0[3][1];
    const float SEm  = red0[0][2] + red0[1][2] + red0[2][2] + red0[3][2];
    const float SmEm = red0[0][3] + red0[1][3] + red0[2][3] + red0[3][3];

    #pragma unroll
    for (int r = 0; r < 2; ++r) {
        const int i = i0 + wid + 4 * r;
        const float l_i = sLj[i];                  // LDS, not global
        const float w_i = sWk[i];
        const float u_i = l_i + w_i;
        const float m_i = 0.5f * (l_i + u_i);
        const float e_li = __expf(-l_i);
        const float e_ui = __expf(-u_i);
        const float e_mi = __expf(-m_i);
        const float ewp  = __expf(w_i);
        const float ewn  = __expf(-w_i);

        float ra = 0.f, rc = 0.f;
        #pragma unroll
        for (int q = 0; q < 4; ++q) {
            const int jb = q * 256 + lane * 4;
            const f32x4 El4 = *reinterpret_cast<const f32x4*>(&sEl[jb]);
            const f32x4 Eu4 = *reinterpret_cast<const f32x4*>(&sEu[jb]);
            const f32x4 Wk4 = *reinterpret_cast<const f32x4*>(&sWk[jb]);
            const f32x4 Lj4 = *reinterpret_cast<const f32x4*>(&sLj[jb]);
            #pragma unroll
            for (int k = 0; k < 4; ++k) {
                const float eu    = Eu4[k] * e_li;
                const float el    = El4[k] * e_ui;
                const float denom = Wk4[k] + w_i;
                float av = (eu - el) * __builtin_amdgcn_rcpf(denom + EPS);
                av = (fabsf(denom) < TINY) ? eu : av;
                ra += av;
                rc = fmaf(av, Lj4[k], rc);
            }
        }
        #pragma unroll
        for (int o = 1; o < 64; o <<= 1) {
            ra += __shfl_xor(ra, o);
            rc += __shfl_xor(rc, o);
        }

        const float S_l  = fmaf(e_ui, SEl, -ewn);
        const float S_u  = fmaf(e_li, SEu, -ewp);
        const float SA_l = fmaf(e_mi, SEm, -1.0f);
        const float SB_l = SA_l - e_mi * SmEm + m_i * e_mi * SEm;

        const float dden = w_i + w_i;
        float a_d = (ewp - ewn) * __builtin_amdgcn_rcpf(dden + EPS);
        a_d = (fabsf(dden) < TINY) ? ewp : a_d;
        const float SA_u = ra - a_d;
        const float rb_full = rc - u_i * ra;       // sum a*(l_j - u_i) incl diag
        const float SBu2 = rb_full + a_d * w_i;    // exclude diag (l_d = -w_i)
        const float SB_u = S_l - SBu2;

        const float g_l = 1.0f / (1.0f + S_l);
        const float g_u = 1.0f / (1.0f + S_u);
        const float dg  = S_u - S_l;
        float m_u = (g_u - g_l) / (dg + EPS);
        m_u = (fabsf(dg) < TINY) ? (-g_u * g_u) : m_u;
        const float c_u = g_l - m_u * S_l;
        const float m_l = -g_u * g_u;
        const float c_l = g_u - m_l * S_u;

        if (lane == 0) {
            const int row = b * C + i;
            out[row]                         = fminf(fmaxf(g_u, 0.f), 1.f); // soft_lower
            out[BC + row]                    = fminf(fmaxf(g_l, 0.f), 1.f); // soft_upper
            out[2 * BC + 2 * BCC + row]      = fmaf(m_l, SB_l, c_l);        // lower bias
            out[2 * BC + 2 * BCC + BC + row] = fmaf(m_u, SB_u, c_u);        // upper bias
            f32x4 w0, w1;
            w0[0] = m_u * e_li; w0[1] = m_u * e_ui; w0[2] = w_i; w0[3] = m_l * e_mi;
            w1[0] = -m_l * SA_l; w1[1] = -m_u * SA_u; w1[2] = 0.f; w1[3] = 0.f;
            *reinterpret_cast<f32x4*>(ws + (long long)row * 8)     = w0;
            *reinterpret_cast<f32x4*>(ws + (long long)row * 8 + 4) = w1;
        }
    }
}

// =====================================================================
// Kernel B: pure streaming writer. All global loads (tables + both rows'
// scalar packs) complete BEFORE the first store; the store phase is
// LDS-reads + VALU + stores only -> no vmcnt drain until kernel end.
// =====================================================================
__global__ __launch_bounds__(256) void stream_kernel(
    const float* __restrict__ lower,
    const float* __restrict__ upper,
    const float* __restrict__ ws,
    float* __restrict__ out)
{
    const int tid  = threadIdx.x;
    const int lane = tid & 63;
    const int wid  = tid >> 6;
    constexpr int rowsPerBatch = C / TI;           // 128
    const int b  = blockIdx.x / rowsPerBatch;
    const int i0 = (blockIdx.x % rowsPerBatch) * TI;

    const float* __restrict__ lrow = lower + b * C;
    const float* __restrict__ urow = upper + b * C;

    __shared__ float sEl[C], sEu[C], sWk[C], sEm[C];   // 16 KB

    const f32x4 lj4 = *reinterpret_cast<const f32x4*>(lrow + tid * 4);
    const f32x4 uj4 = *reinterpret_cast<const f32x4*>(urow + tid * 4);
    f32x4 tEl, tEu, tWk, tEm;
    #pragma unroll
    for (int k = 0; k < 4; ++k) {
        const float lj = lj4[k];
        const float uj = uj4[k];
        tEl[k] = __expf(lj);
        tEu[k] = __expf(uj);
        tWk[k] = uj - lj;
        tEm[k] = __expf(0.5f * (lj + uj));
    }
    *reinterpret_cast<f32x4*>(&sEl[tid * 4]) = tEl;
    *reinterpret_cast<f32x4*>(&sEu[tid * 4]) = tEu;
    *reinterpret_cast<f32x4*>(&sWk[tid * 4]) = tWk;
    *reinterpret_cast<f32x4*>(&sEm[tid * 4]) = tEm;

    // preload BOTH rows' scalar packs before any store
    const int iA = i0 + wid;
    const int iB = i0 + wid + 4;
    const long long rowA = (long long)b * C + iA;
    const long long rowB = (long long)b * C + iB;
    const f32x4 pA0 = *reinterpret_cast<const f32x4*>(ws + rowA * 8);
    const f32x4 pA1 = *reinterpret_cast<const f32x4*>(ws + rowA * 8 + 4);
    const f32x4 pB0 = *reinterpret_cast<const f32x4*>(ws + rowB * 8);
    const f32x4 pB1 = *reinterpret_cast<const f32x4*>(ws + rowB * 8 + 4);
    const float alA = pA0[0], beA = pA0[1], wA = pA0[2], KlA = pA0[3];
    const float dlA = pA1[0], duA = pA1[1];
    const float alB = pB0[0], beB = pB0[1], wB = pB0[2], KlB = pB0[3];
    const float dlB = pB1[0], duB = pB1[1];

    float* __restrict__ lcA = out + 2 * BC + rowA * C;
    float* __restrict__ ucA = out + 2 * BC + BCC + rowA * C;
    float* __restrict__ lcB = out + 2 * BC + rowB * C;
    float* __restrict__ ucB = out + 2 * BC + BCC + rowB * C;

    __syncthreads();

    #pragma unroll
    for (int q = 0; q < 4; ++q) {
        const int jb = q * 256 + lane * 4;
        const f32x4 El4 = *reinterpret_cast<const f32x4*>(&sEl[jb]);
        const f32x4 Eu4 = *reinterpret_cast<const f32x4*>(&sEu[jb]);
        const f32x4 Wk4 = *reinterpret_cast<const f32x4*>(&sWk[jb]);
        const f32x4 Em4 = *reinterpret_cast<const f32x4*>(&sEm[jb]);
        f32x4 lvA, uvA, lvB, uvB;
        #pragma unroll
        for (int k = 0; k < 4; ++k) {
            const int j = jb + k;
            // row A
            {
                const float u0    = Eu4[k] * alA;          // m_u * eu
                const float e0    = El4[k] * beA;          // m_u * el
                const float denom = Wk4[k] + wA;
                float a = (u0 - e0) * __builtin_amdgcn_rcpf(denom + EPS);
                a = (fabsf(denom) < TINY) ? u0 : a;
                uvA[k] = (j == iA) ? duA : a;
                lvA[k] = (j == iA) ? dlA : KlA * Em4[k];
            }
            // row B
            {
                const float u0    = Eu4[k] * alB;
                const float e0    = El4[k] * beB;
                const float denom = Wk4[k] + wB;
                float a = (u0 - e0) * __builtin_amdgcn_rcpf(denom + EPS);
                a = (fabsf(denom) < TINY) ? u0 : a;
                uvB[k] = (j == iB) ? duB : a;
                lvB[k] = (j == iB) ? dlB : KlB * Em4[k];
            }
        }
        *reinterpret_cast<f32x4*>(lcA + jb) = lvA;
        *reinterpret_cast<f32x4*>(ucA + jb) = uvA;
        *reinterpret_cast<f32x4*>(lcB + jb) = lvB;
        *reinterpret_cast<f32x4*>(ucB + jb) = uvB;
    }
}

// =====================================================================
// Fallback: R2 fused kernel (used only if ws is unusable)
// =====================================================================
__global__ __launch_bounds__(256) void bounded_softmax_fused(
    const float* __restrict__ lower,
    const float* __restrict__ upper,
    float* __restrict__ out)
{
    const int tid  = threadIdx.x;
    const int lane = tid & 63;
    const int wid  = tid >> 6;
    constexpr int rowsPerBatch = C / TI;
    const int b  = blockIdx.x / rowsPerBatch;
    const int i0 = (blockIdx.x % rowsPerBatch) * TI;

    const float* __restrict__ lrow = lower + b * C;
    const float* __restrict__ urow = upper + b * C;

    __shared__ float sEl[C], sEu[C], sWk[C], sEm[C];
    __shared__ float red0[4][4];

    const f32x4 lj4 = *reinterpret_cast<const f32x4*>(lrow + tid * 4);
    const f32x4 uj4 = *reinterpret_cast<const f32x4*>(urow + tid * 4);
    f32x4 tEl, tEu, tWk, tEm;
    float s0 = 0.f, s1 = 0.f, s2 = 0.f, s3 = 0.f;
    #pragma unroll
    for (int k = 0; k < 4; ++k) {
        const float lj = lj4[k];
        const float uj = uj4[k];
        const float El = __expf(lj);
        const float Eu = __expf(uj);
        const float mk = 0.5f * (lj + uj);
        const float Em = __expf(mk);
        tEl[k] = El; tEu[k] = Eu; tWk[k] = uj - lj; tEm[k] = Em;
        s0 += El; s1 += Eu; s2 += Em; s3 += mk * Em;
    }
    *reinterpret_cast<f32x4*>(&sEl[tid * 4]) = tEl;
    *reinterpret_cast<f32x4*>(&sEu[tid * 4]) = tEu;
    *reinterpret_cast<f32x4*>(&sWk[tid * 4]) = tWk;
    *reinterpret_cast<f32x4*>(&sEm[tid * 4]) = tEm;
    #pragma unroll
    for (int o = 32; o > 0; o >>= 1) {
        s0 += __shfl_down(s0, o);
        s1 += __shfl_down(s1, o);
        s2 += __shfl_down(s2, o);
        s3 += __shfl_down(s3, o);
    }
    if (lane == 0) {
        red0[wid][0] = s0; red0[wid][1] = s1;
        red0[wid][2] = s2; red0[wid][3] = s3;
    }
    __syncthreads();
    const float SEl  = red0[0][0] + red0[1][0] + red0[2][0] + red0[3][0];
    const float SEu  = red0[0][1] + red0[1][1] + red0[2][1] + red0[3][1];
    const float SEm  = red0[0][2] + red0[1][2] + red0[2][2] + red0[3][2];
    const float SmEm = red0[0][3] + red0[1][3] + red0[2][3] + red0[3][3];

    #pragma unroll
    for (int r = 0; r < 2; ++r) {
        const int i = i0 + wid + 4 * r;
        const float l_i = lrow[i];
        const float u_i = urow[i];
        const float w_i = u_i - l_i;
        const float m_i = 0.5f * (l_i + u_i);
        const float e_li = __expf(-l_i);
        const float e_ui = __expf(-u_i);
        const float e_mi = __expf(-m_i);
        const float ewp  = __expf(w_i);
        const float ewn  = __expf(-w_i);

        float a[16];
        float ra = 0.f, rc = 0.f;
        #pragma unroll
        for (int q = 0; q < 4; ++q) {
            const int jb = q * 256 + lane * 4;
            const f32x4 El4 = *reinterpret_cast<const f32x4*>(&sEl[jb]);
            const f32x4 Eu4 = *reinterpret_cast<const f32x4*>(&sEu[jb]);
            const f32x4 Wk4 = *reinterpret_cast<const f32x4*>(&sWk[jb]);
            const f32x4 Lj4 = *reinterpret_cast<const f32x4*>(lrow + jb);
            #pragma unroll
            for (int k = 0; k < 4; ++k) {
                const float eu    = Eu4[k] * e_li;
                const float el    = El4[k] * e_ui;
                const float denom = Wk4[k] + w_i;
                float av = (eu - el) * __builtin_amdgcn_rcpf(denom + EPS);
                av = (fabsf(denom) < TINY) ? eu : av;
                a[q * 4 + k] = av;
                ra += av;
                rc = fmaf(av, Lj4[k], rc);
            }
        }
        #pragma unroll
        for (int o = 1; o < 64; o <<= 1) {
            ra += __shfl_xor(ra, o);
            rc += __shfl_xor(rc, o);
        }

        const float S_l  = fmaf(e_ui, SEl, -ewn);
        const float S_u  = fmaf(e_li, SEu, -ewp);
        const float SA_l = fmaf(e_mi, SEm, -1.0f);
        const float SB_l = SA_l - e_mi * SmEm + m_i * e_mi * SEm;

        const float dden = w_i + w_i;
        float a_d = (ewp - ewn) * __builtin_amdgcn_rcpf(dden + EPS);
        a_d = (fabsf(dden) < TINY) ? ewp : a_d;
        const float SA_u = ra - a_d;
        const float rb_full = rc - u_i * ra;
        const float SBu2 = rb_full + a_d * w_i;
        const float SB_u = S_l - SBu2;

        const float g_l = 1.0f / (1.0f + S_l);
        const float g_u = 1.0f / (1.0f + S_u);
        const float dg  = S_u - S_l;
        float m_u = (g_u - g_l) / (dg + EPS);
        m_u = (fabsf(dg) < TINY) ? (-g_u * g_u) : m_u;
        const float c_u = g_l - m_u * S_l;
        const float m_l = -g_u * g_u;
        const float c_l = g_u - m_l * S_u;

        const int row = b * C + i;
        float* __restrict__ lower_coef = out + 2 * BC + (long long)row * C;
        float* __restrict__ upper_coef = out + 2 * BC + BCC + (long long)row * C;

        const float Kl = m_l * e_mi;
        const float dl = -m_l * SA_l;
        const float du = -m_u * SA_u;
        #pragma unroll
        for (int q = 0; q < 4; ++q) {
            const int jb = q * 256 + lane * 4;
            const f32x4 Em4 = *reinterpret_cast<const f32x4*>(&sEm[jb]);
            f32x4 lv, uv;
            #pragma unroll
            for (int k = 0; k < 4; ++k) {
                const int j = jb + k;
                lv[k] = (j == i) ? dl : Kl * Em4[k];
                uv[k] = (j == i) ? du : m_u * a[q * 4 + k];
            }
            *reinterpret_cast<f32x4*>(lower_coef + jb) = lv;
            *reinterpret_cast<f32x4*>(upper_coef + jb) = uv;
        }

        if (lane == 0) {
            out[row]                         = fminf(fmaxf(g_u, 0.f), 1.f);
            out[BC + row]                    = fminf(fmaxf(g_l, 0.f), 1.f);
            out[2 * BC + 2 * BCC + row]      = fmaf(m_l, SB_l, c_l);
            out[2 * BC + 2 * BCC + BC + row] = fmaf(m_u, SB_u, c_u);
        }
    }
}

} // namespace

extern "C" void kernel_launch(void* const* d_in, const int* in_sizes, int n_in,
                              void* d_out, int out_size, void* d_ws, size_t ws_size,
                              hipStream_t stream) {
    const float* lower = (const float*)d_in[0];
    const float* upper = (const float*)d_in[1];
    float* out = (float*)d_out;
    const size_t wsNeeded = (size_t)BC * 8 * sizeof(float);   // 512 KB
    if (d_ws != nullptr && ws_size >= wsNeeded) {
        rowscalar_kernel<<<dim3(BC / TI), dim3(256), 0, stream>>>(
            lower, upper, out, (float*)d_ws);
        stream_kernel<<<dim3(BC / TI), dim3(256), 0, stream>>>(
            lower, upper, (const float*)d_ws, out);
    } else {
        bounded_softmax_fused<<<dim3(BC / TI), dim3(256), 0, stream>>>(
            lower, upper, out);
    }
}

// Round 4
// 138.212 us; speedup vs baseline: 1.0786x; 1.0786x over previous
//
#include <hip/hip_runtime.h>

namespace {

constexpr int B = 16;
constexpr int C = 1024;
constexpr int BC = B * C;                          // 16384
constexpr long long BCC = (long long)B * C * C;    // 16777216
constexpr float EPS  = 1e-12f;
constexpr float TINY = 1e-9f;
constexpr int RPB = 16;                            // rows per block (4 per wave)
// grid = 2*(BC/RPB) = 2048 blocks x 256 threads.
// Even blocks: lower_coef stream only. Odd blocks: upper_coef stream only.
// Each wave writes ONE contiguous ascending 16 KB region (4 rows x 4 KB) --
// mimics fillBuffer's per-WG single-stream pattern for DRAM row locality.

using f32x4 = __attribute__((ext_vector_type(4))) float;

__global__ __launch_bounds__(256) void bounded_softmax_split(
    const float* __restrict__ lower,
    const float* __restrict__ upper,
    float* __restrict__ out)
{
    const int tid  = threadIdx.x;
    const int lane = tid & 63;
    const int wid  = tid >> 6;
    const int blk  = blockIdx.x;
    const bool isUpper = (blk & 1) != 0;
    const int rowBase  = (blk >> 1) * RPB;         // 0..16368
    const int b  = rowBase >> 10;                  // C == 1024
    const int i0 = rowBase & (C - 1);

    const float* __restrict__ lrow = lower + b * C;
    const float* __restrict__ urow = upper + b * C;

    __shared__ float sA [C];   // upper: exp(l_j) ; lower: exp(m_j)
    __shared__ float sEu[C];   // exp(u_j) (upper blocks)
    __shared__ float sWk[C];   // u_j - l_j
    __shared__ float sLj[C];   // l_j
    __shared__ float red0[4][4];

    // ---- table build + batch sums ----
    const f32x4 lj4 = *reinterpret_cast<const f32x4*>(lrow + tid * 4);
    const f32x4 uj4 = *reinterpret_cast<const f32x4*>(urow + tid * 4);
    f32x4 tA, tEu, tWk;
    float s0 = 0.f, s1 = 0.f, s2 = 0.f, s3 = 0.f;  // sum El, Eu, Em, m*Em
    #pragma unroll
    for (int k = 0; k < 4; ++k) {
        const float lj = lj4[k];
        const float uj = uj4[k];
        const float El = __expf(lj);
        const float Eu = __expf(uj);
        const float mk = 0.5f * (lj + uj);
        const float Em = __expf(mk);
        tA[k]  = isUpper ? El : Em;
        tEu[k] = Eu;
        tWk[k] = uj - lj;
        s0 += El; s1 += Eu; s2 += Em; s3 += mk * Em;
    }
    *reinterpret_cast<f32x4*>(&sA [tid * 4]) = tA;
    *reinterpret_cast<f32x4*>(&sEu[tid * 4]) = tEu;
    *reinterpret_cast<f32x4*>(&sWk[tid * 4]) = tWk;
    *reinterpret_cast<f32x4*>(&sLj[tid * 4]) = lj4;
    #pragma unroll
    for (int o = 32; o > 0; o >>= 1) {
        s0 += __shfl_down(s0, o);
        s1 += __shfl_down(s1, o);
        s2 += __shfl_down(s2, o);
        s3 += __shfl_down(s3, o);
    }
    if (lane == 0) {
        red0[wid][0] = s0; red0[wid][1] = s1;
        red0[wid][2] = s2; red0[wid][3] = s3;
    }
    __syncthreads();                               // the only barrier
    const float SEl  = red0[0][0] + red0[1][0] + red0[2][0] + red0[3][0];
    const float SEu  = red0[0][1] + red0[1][1] + red0[2][1] + red0[3][1];
    const float SEm  = red0[0][2] + red0[1][2] + red0[2][2] + red0[3][2];
    const float SmEm = red0[0][3] + red0[1][3] + red0[2][3] + red0[3][3];

    if (!isUpper) {
        // ================= LOWER-coef blocks: pure closed form =================
        float* __restrict__ base = out + 2 * BC;
        #pragma unroll
        for (int r = 0; r < 4; ++r) {
            const int i = i0 + wid * 4 + r;        // wave's rows ascending
            const float l_i = sLj[i];
            const float w_i = sWk[i];
            const float m_i = l_i + 0.5f * w_i;
            const float e_li = __expf(-l_i);
            const float e_mi = __expf(-m_i);
            const float ewp  = __expf(w_i);
            const float S_u  = fmaf(e_li, SEu, -ewp);
            const float SA_l = fmaf(e_mi, SEm, -1.0f);
            const float SB_l = SA_l - e_mi * SmEm + m_i * e_mi * SEm;
            const float g_u  = 1.0f / (1.0f + S_u);
            const float m_l  = -g_u * g_u;
            const float c_l  = g_u - m_l * S_u;
            const float Kl   = m_l * e_mi;
            const float dl   = -m_l * SA_l;

            const long long row = (long long)b * C + i;
            float* __restrict__ dst = base + row * C;
            #pragma unroll
            for (int q = 0; q < 4; ++q) {
                const int jb = q * 256 + lane * 4;
                const f32x4 Em4 = *reinterpret_cast<const f32x4*>(&sA[jb]);
                f32x4 lv;
                #pragma unroll
                for (int k = 0; k < 4; ++k) {
                    const int j = jb + k;
                    lv[k] = (j == i) ? dl : Kl * Em4[k];
                }
                *reinterpret_cast<f32x4*>(dst + jb) = lv;
            }
            if (lane == 0) {
                out[row]                    = fminf(fmaxf(g_u, 0.f), 1.f); // soft_lower
                out[2 * BC + 2 * BCC + row] = fmaf(m_l, SB_l, c_l);        // lower bias
            }
        }
    } else {
        // ================= UPPER-coef blocks: self-sufficient =================
        float* __restrict__ base = out + 2 * BC + BCC;
        #pragma unroll
        for (int r = 0; r < 4; ++r) {
            const int i = i0 + wid * 4 + r;
            const float l_i = sLj[i];
            const float w_i = sWk[i];
            const float u_i = l_i + w_i;
            const float e_li = __expf(-l_i);
            const float e_ui = __expf(-u_i);
            const float ewp  = __expf(w_i);
            const float ewn  = __expf(-w_i);
            const float S_l  = fmaf(e_ui, SEl, -ewn);
            const float S_u  = fmaf(e_li, SEu, -ewp);
            const float g_l  = 1.0f / (1.0f + S_l);
            const float g_u  = 1.0f / (1.0f + S_u);
            const float dg   = S_u - S_l;
            float m_u = (g_u - g_l) / (dg + EPS);  // closed-form: no reduction needed
            m_u = (fabsf(dg) < TINY) ? (-g_u * g_u) : m_u;
            const float c_u = g_l - m_u * S_l;

            float a[16];
            float ra = 0.f, rc = 0.f;
            #pragma unroll
            for (int q = 0; q < 4; ++q) {
                const int jb = q * 256 + lane * 4;
                const f32x4 El4 = *reinterpret_cast<const f32x4*>(&sA [jb]);
                const f32x4 Eu4 = *reinterpret_cast<const f32x4*>(&sEu[jb]);
                const f32x4 Wk4 = *reinterpret_cast<const f32x4*>(&sWk[jb]);
                const f32x4 Lj4 = *reinterpret_cast<const f32x4*>(&sLj[jb]);
                #pragma unroll
                for (int k = 0; k < 4; ++k) {
                    const float eu    = Eu4[k] * e_li;
                    const float el    = El4[k] * e_ui;
                    const float denom = Wk4[k] + w_i;
                    float av = (eu - el) * __builtin_amdgcn_rcpf(denom + EPS);
                    av = (fabsf(denom) < TINY) ? eu : av;
                    a[q * 4 + k] = av;
                    ra += av;
                    rc = fmaf(av, Lj4[k], rc);
                }
            }
            #pragma unroll
            for (int o = 1; o < 64; o <<= 1) {     // butterfly: totals in all lanes
                ra += __shfl_xor(ra, o);
                rc += __shfl_xor(rc, o);
            }
            const float dden = w_i + w_i;
            float a_d = (ewp - ewn) * __builtin_amdgcn_rcpf(dden + EPS);
            a_d = (fabsf(dden) < TINY) ? ewp : a_d;
            const float SA_u    = ra - a_d;
            const float rb_full = rc - u_i * ra;   // sum a*(l_j - u_i) incl diag
            const float SBu2    = rb_full + a_d * w_i;
            const float SB_u    = S_l - SBu2;
            const float du      = -m_u * SA_u;

            const long long row = (long long)b * C + i;
            float* __restrict__ dst = base + row * C;
            #pragma unroll
            for (int q = 0; q < 4; ++q) {
                const int jb = q * 256 + lane * 4;
                f32x4 uv;
                #pragma unroll
                for (int k = 0; k < 4; ++k) {
                    const int j = jb + k;
                    uv[k] = (j == i) ? du : m_u * a[q * 4 + k];
                }
                *reinterpret_cast<f32x4*>(dst + jb) = uv;
            }
            if (lane == 0) {
                out[BC + row]                    = fminf(fmaxf(g_l, 0.f), 1.f); // soft_upper
                out[2 * BC + 2 * BCC + BC + row] = fmaf(m_u, SB_u, c_u);        // upper bias
            }
        }
    }
}

} // namespace

extern "C" void kernel_launch(void* const* d_in, const int* in_sizes, int n_in,
                              void* d_out, int out_size, void* d_ws, size_t ws_size,
                              hipStream_t stream) {
    const float* lower = (const float*)d_in[0];
    const float* upper = (const float*)d_in[1];
    float* out = (float*)d_out;
    bounded_softmax_split<<<dim3(2 * (BC / RPB)), dim3(256), 0, stream>>>(
        lower, upper, out);
}